// Round 5
// baseline (356.048 us; speedup 1.0000x reference)
//
#include <hip/hip_runtime.h>

// Problem constants (fixed by setup_inputs)
#define HW   256
#define Bb   4
#define Nn   256       // B*K flattened keypoints
#define Pp   33
#define PPAD 36        // padded patch row
#define OUTF 128
#define SIG  16

// strip: [kc2][R31][col 36]; stride 36 spreads banks (R2 fix: 36%32=4)
#define SSTR 36
#define SKC  (31 * SSTR)   // 1116

// ws layout (float offsets)
#define WS_W1R  0        // [32][28]   = 896 (per-channel k-major, pad 27->28)
#define WS_W2T  896      // [288][64]  = 18432 (k=(kc*3+ky)*3+kx major, ch minor)
#define WS_WLT  19328    // [64][128]  = 8192
#define WS_FEAT 27520    // 2*256*4*128 = 262144
#define WS_PART 289664   // 64 doubles (byte offset 1158656, 8B aligned)
#define FEAT_PER_SIDE (Nn * Bb * OUTF)   // 131072

__global__ __launch_bounds__(256) void prep_kernel(
    const float* __restrict__ w1, const float* __restrict__ w2,
    const float* __restrict__ wl, float* __restrict__ ws) {
  int t = blockIdx.x * 256 + threadIdx.x;
  int stride = gridDim.x * 256;
  for (int i = t; i < 896; i += stride) {        // w1r[ch][28]
    int ch = i / 28, k = i - ch * 28;
    ws[WS_W1R + i] = (k < 27) ? w1[ch * 27 + k] : 0.0f;
  }
  for (int i = t; i < 18432; i += stride) {      // w2t[k288][ch64]
    int ch = i & 63, k = i >> 6;
    ws[WS_W2T + i] = w2[ch * 288 + k];
  }
  for (int i = t; i < 8192; i += stride) {       // wlt[i64][o128]
    int o = i & 127, ii = i >> 7;
    ws[WS_WLT + i] = wl[o * 64 + ii];
  }
}

// ---- pipeline stages as plain inline functions (no macros) ----

__device__ __forceinline__ void stage_w2(const float* __restrict__ ws, int chunk,
                                         float* __restrict__ dstW, int tid) {
  // copy 1152 floats (= 288 float4) for 2 input channels
  const float4* src = (const float4*)(ws + WS_W2T + chunk * 1152);
  float4* dst = (float4*)dstW;
  dst[tid] = src[tid];
  if (tid < 32) dst[tid + 256] = src[tid + 256];
}

__device__ __forceinline__ void conv1_chunk(const float* __restrict__ patch,
                                            const float* __restrict__ w1l,
                                            const float* __restrict__ b1l,
                                            float* __restrict__ stripBuf,
                                            int chunk, int kcl, int tpos, int rslot) {
  const int ch1 = chunk * 2 + kcl;
  const float bb = b1l[ch1];
  float4 wv[7];
  const float4* wsrc = (const float4*)&w1l[ch1 * 28];
#pragma unroll
  for (int q = 0; q < 7; ++q) wv[q] = wsrc[q];
  const float* wr = (const float*)wv;
  float* sptr = stripBuf + kcl * SKC + tpos * 4;
#pragma unroll
  for (int rr = 0; rr < 2; ++rr) {
    const int R = rslot + rr * 16;
    if (R < 31) {
      float a0 = bb, a1 = bb, a2 = bb, a3 = bb;
#pragma unroll
      for (int ci = 0; ci < 3; ++ci) {
#pragma unroll
        for (int ky = 0; ky < 3; ++ky) {
          const float* pr = &patch[(ci * Pp + R + ky) * PPAD + tpos * 4];
          float4 v0 = *(const float4*)pr;
          float2 v1 = *(const float2*)(pr + 4);
          const int k = (ci * 3 + ky) * 3;
          a0 = fmaf(v0.z, wr[k + 2], fmaf(v0.y, wr[k + 1], fmaf(v0.x, wr[k], a0)));
          a1 = fmaf(v0.w, wr[k + 2], fmaf(v0.z, wr[k + 1], fmaf(v0.y, wr[k], a1)));
          a2 = fmaf(v1.x, wr[k + 2], fmaf(v0.w, wr[k + 1], fmaf(v0.z, wr[k], a2)));
          a3 = fmaf(v1.y, wr[k + 2], fmaf(v1.x, wr[k + 1], fmaf(v0.w, wr[k], a3)));
        }
      }
      float4 o;
      o.x = fmaxf(a0, 0.f); o.y = fmaxf(a1, 0.f);
      o.z = fmaxf(a2, 0.f); o.w = fmaxf(a3, 0.f);
      *(float4*)(sptr + R * SSTR) = o;
    }
  }
}

__device__ __forceinline__ void conv2_chunk(const float* __restrict__ stripBuf,
                                            const float* __restrict__ w2cBuf,
                                            float4* __restrict__ acc,
                                            int y2, int chg, bool act) {
  if (!act) return;
  const float* sbase = stripBuf + 2 * y2 * SSTR;
#pragma unroll
  for (int kc = 0; kc < 2; ++kc) {
    const float* srow = sbase + kc * SKC;
    const float4* wk = (const float4*)&w2cBuf[kc * 576 + 4 * chg];
    float4 wq[9];
#pragma unroll
    for (int q = 0; q < 9; ++q) wq[q] = wk[q * 16];
#pragma unroll
    for (int ky = 0; ky < 3; ++ky) {
      float v[32];
      const float4* sv = (const float4*)(srow + ky * SSTR);
#pragma unroll
      for (int j = 0; j < 8; ++j) ((float4*)v)[j] = sv[j];
      const float4 w0 = wq[ky * 3], w1v = wq[ky * 3 + 1], w2v = wq[ky * 3 + 2];
#pragma unroll
      for (int x = 0; x < 15; ++x) {
        float4 a = acc[x];
        a.x = fmaf(v[2*x+2], w2v.x, fmaf(v[2*x+1], w1v.x, fmaf(v[2*x], w0.x, a.x)));
        a.y = fmaf(v[2*x+2], w2v.y, fmaf(v[2*x+1], w1v.y, fmaf(v[2*x], w0.y, a.y)));
        a.z = fmaf(v[2*x+2], w2v.z, fmaf(v[2*x+1], w1v.z, fmaf(v[2*x], w0.z, a.z)));
        a.w = fmaf(v[2*x+2], w2v.w, fmaf(v[2*x+1], w1v.w, fmaf(v[2*x], w0.w, a.w)));
        acc[x] = a;
      }
    }
  }
}

// One block per patch. 256 threads = 4 waves.
// kc-chunks of 2 input channels (16 chunks), double-buffered strip + w2c,
// explicit even/odd pipeline: stage/conv1 for chunk c+1 overlaps conv2 of chunk c.
__global__ __launch_bounds__(256, 3) void patch_cnn_kernel(
    const float* __restrict__ imgG, const float* __restrict__ imgS,
    const float* __restrict__ kpG,  const float* __restrict__ kpS,
    const float* __restrict__ b1g,  const float* __restrict__ b2g,
    const float* __restrict__ blg,  float* __restrict__ ws) {
  __shared__ __align__(16) float patch[3 * Pp * PPAD];   // 3564 f
  __shared__ __align__(16) float strip0[2 * SKC];        // 2232 f
  __shared__ __align__(16) float strip1[2 * SKC];        // 2232 f
  __shared__ __align__(16) float w2c0[2 * 9 * 64];       // 1152 f
  __shared__ __align__(16) float w2c1[2 * 9 * 64];       // 1152 f
  __shared__ __align__(16) float w1l[32 * 28];           // 896 f
  __shared__ float b1l[32];
  __shared__ __align__(16) float gapP[16 * 64];          // 1024 f
  __shared__ float gapv[64];
  // total = 49,392 B -> 3 blocks/CU

  const int bid  = blockIdx.x;
  const int side = bid >> 10;
  const int rem  = bid & 1023;
  const int n    = rem >> 2;
  const int b    = rem & 3;
  const float* img = side ? imgS : imgG;
  const float* kp  = side ? kpS : kpG;
  const int tid  = threadIdx.x;
  const int wave = tid >> 6;
  const int lane = tid & 63;

  // conv1 lane mapping: tpos = cols, kcl = channel parity, rslot = row slot
  const int tpos  = lane & 7;
  const int kcl   = (lane >> 3) & 1;
  const int rslot = wave * 4 + (lane >> 4);   // 0..15; rows rslot, rslot+16 (<31)
  // conv2 thread mapping
  const int y2  = tid >> 4;       // 0..15 (15 = inactive)
  const int chg = tid & 15;
  const bool c2act = (y2 < 15);

  int sx = (int)floorf(kp[n * 2 + 0] * 256.0f) - SIG;
  int sy = (int)floorf(kp[n * 2 + 1] * 256.0f) - SIG;
  sx = min(max(sx, 0), HW - Pp);
  sy = min(max(sy, 0), HW - Pp);

  // stage patch (zero pad cols)
  for (int i = tid; i < 3 * Pp * PPAD; i += 256) {
    int ci = i / (Pp * PPAD);
    int r2 = i - ci * (Pp * PPAD);
    int r  = r2 / PPAD;
    int cc = r2 - r * PPAD;
    float v = 0.0f;
    if (cc < Pp) v = img[((b * 3 + ci) * HW + (sy + r)) * HW + (sx + cc)];
    patch[i] = v;
  }
  for (int i = tid; i < 896; i += 256) w1l[i] = ws[WS_W1R + i];
  if (tid < 32) b1l[tid] = b1g[tid];

  float4 acc[15];
#pragma unroll
  for (int x = 0; x < 15; ++x) acc[x] = make_float4(0.f, 0.f, 0.f, 0.f);

  __syncthreads();

  // prologue: chunk 0 -> buffer 0
  stage_w2(ws, 0, w2c0, tid);
  conv1_chunk(patch, w1l, b1l, strip0, 0, kcl, tpos, rslot);
  __syncthreads();

#pragma unroll 1
  for (int c = 0; c < 16; c += 2) {
    // even half-step: produce chunk c+1 -> buf1, consume chunk c <- buf0
    stage_w2(ws, c + 1, w2c1, tid);
    conv1_chunk(patch, w1l, b1l, strip1, c + 1, kcl, tpos, rslot);
    conv2_chunk(strip0, w2c0, acc, y2, chg, c2act);
    __syncthreads();
    // odd half-step: produce chunk c+2 -> buf0, consume chunk c+1 <- buf1
    if (c + 2 < 16) {
      stage_w2(ws, c + 2, w2c0, tid);
      conv1_chunk(patch, w1l, b1l, strip0, c + 2, kcl, tpos, rslot);
    }
    conv2_chunk(strip1, w2c1, acc, y2, chg, c2act);
    __syncthreads();
  }

  // epilogue: bias + relu + GAP partial per (y2, 4ch)
  if (c2act) {
    const float4 b2v = *(const float4*)(b2g + 4 * chg);
    float4 s = make_float4(0.f, 0.f, 0.f, 0.f);
#pragma unroll
    for (int x = 0; x < 15; ++x) {
      s.x += fmaxf(acc[x].x + b2v.x, 0.f);
      s.y += fmaxf(acc[x].y + b2v.y, 0.f);
      s.z += fmaxf(acc[x].z + b2v.z, 0.f);
      s.w += fmaxf(acc[x].w + b2v.w, 0.f);
    }
    *(float4*)&gapP[y2 * 64 + 4 * chg] = s;
  } else {
    *(float4*)&gapP[15 * 64 + 4 * (tid - 240)] = make_float4(0.f, 0.f, 0.f, 0.f);
  }
  __syncthreads();
  if (tid < 64) {
    float s = 0.f;
#pragma unroll
    for (int y = 0; y < 16; ++y) s += gapP[y * 64 + tid];
    gapv[tid] = s * (1.0f / 225.0f);
  }
  __syncthreads();
  if (tid < OUTF) {
    float f = blg[tid];
#pragma unroll 8
    for (int i = 0; i < 64; ++i) f = fmaf(gapv[i], ws[WS_WLT + i * OUTF + tid], f);
    ws[WS_FEAT + ((side * Nn + n) * Bb + b) * OUTF + tid] = f;
  }
}

__global__ __launch_bounds__(256) void loss_part(const float* __restrict__ wsf,
                                                 double* __restrict__ parts) {
  const float* fg = wsf + WS_FEAT;
  const float* fs = fg + FEAT_PER_SIDE;
  double s = 0.0;
  for (int i = blockIdx.x * 256 + threadIdx.x; i < FEAT_PER_SIDE; i += 64 * 256) {
    double d = (double)fg[i] - (double)fs[i];
    s += d * d;
  }
  __shared__ double red[256];
  red[threadIdx.x] = s;
  __syncthreads();
  for (int off = 128; off > 0; off >>= 1) {
    if (threadIdx.x < off) red[threadIdx.x] += red[threadIdx.x + off];
    __syncthreads();
  }
  if (threadIdx.x == 0) parts[blockIdx.x] = red[0];
}

__global__ void loss_final(float* __restrict__ out, const double* __restrict__ parts) {
  double s = parts[threadIdx.x];
#pragma unroll
  for (int off = 32; off > 0; off >>= 1) s += __shfl_down(s, off, 64);
  if (threadIdx.x == 0) out[0] = (float)(s / (double)FEAT_PER_SIDE);
}

extern "C" void kernel_launch(void* const* d_in, const int* in_sizes, int n_in,
                              void* d_out, int out_size, void* d_ws, size_t ws_size,
                              hipStream_t stream) {
  const float* imgG = (const float*)d_in[0];
  const float* imgS = (const float*)d_in[1];
  const float* kpG  = (const float*)d_in[2];
  const float* kpS  = (const float*)d_in[3];
  const float* w1   = (const float*)d_in[4];
  const float* b1   = (const float*)d_in[5];
  const float* w2   = (const float*)d_in[6];
  const float* b2   = (const float*)d_in[7];
  const float* wl   = (const float*)d_in[8];
  const float* bl   = (const float*)d_in[9];
  float* ws  = (float*)d_ws;
  float* out = (float*)d_out;
  double* parts = (double*)((char*)d_ws + (size_t)WS_PART * 4);

  hipLaunchKernelGGL(prep_kernel, dim3(32), dim3(256), 0, stream, w1, w2, wl, ws);
  hipLaunchKernelGGL(patch_cnn_kernel, dim3(2048), dim3(256), 0, stream,
                     imgG, imgS, kpG, kpS, b1, b2, bl, ws);
  hipLaunchKernelGGL(loss_part, dim3(64), dim3(256), 0, stream, ws, parts);
  hipLaunchKernelGGL(loss_final, dim3(1), dim3(64), 0, stream, out, parts);
}

// Round 6
// 189.850 us; speedup vs baseline: 1.8754x; 1.8754x over previous
//
#include <hip/hip_runtime.h>

// Problem constants (fixed by setup_inputs)
#define HW   256
#define Bb   4
#define Nn   256       // B*K flattened keypoints
#define Pp   33
#define PPAD 36        // padded patch row (float)
#define OUTF 128
#define SIG  16

// conv1-output planes for MFMA A-operands:
// [rowslot 6][parity 2][col' 16][kc 40 (32 used + 8 pad)] ushort, hi & lo planes.
// col'-stride = 80 B (16B-aligned b128 reads; bank shift 20 -> <=2-way).
#define KCP   40
#define PLROW (2 * 16 * KCP)       // shorts per row-slot = 1280
#define PLSZ  (6 * PLROW)          // 7680 shorts per plane

// ws layout (float offsets)
#define WS_W1R  0        // [32][28] f32 = 896 (per-channel k-major, pad 27->28)
#define WS_BHI  896      // 18432 ushort = 9216 f  (B-frags hi, frag-ordered)
#define WS_BLO  10112    // 18432 ushort = 9216 f  (B-frags lo)
#define WS_WLT  19328    // [64][128] f32 = 8192
#define WS_FEAT 27520    // 2*256*4*128 = 262144
#define WS_PART 289664   // 64 doubles (byte 1158656, 8B aligned)
#define FEAT_PER_SIDE (Nn * Bb * OUTF)   // 131072

typedef __attribute__((ext_vector_type(8))) short v8s;    // 8 bf16 (4 VGPRs)
typedef __attribute__((ext_vector_type(4))) float f32x4;  // MFMA acc

__device__ __forceinline__ unsigned short f2bf_rne(float x) {
  unsigned u = __float_as_uint(x);
  unsigned r = (u + 0x7FFFu + ((u >> 16) & 1u)) >> 16;
  return (unsigned short)r;
}
__device__ __forceinline__ float bf2f(unsigned short h) {
  return __uint_as_float(((unsigned)h) << 16);
}

__global__ __launch_bounds__(256) void prep_kernel(
    const float* __restrict__ w1, const float* __restrict__ w2,
    const float* __restrict__ wl, float* __restrict__ ws) {
  int t = blockIdx.x * 256 + threadIdx.x;
  int stride = gridDim.x * 256;
  for (int i = t; i < 896; i += stride) {        // w1r[ch][28]
    int ch = i / 28, k = i - ch * 28;
    ws[WS_W1R + i] = (k < 27) ? w1[ch * 27 + k] : 0.0f;
  }
  // B-fragments for mfma_f32_16x16x32_bf16:
  // element j of lane l, wave w, tap t: n(ch) = w*16 + (l&15), k(kc) = (l>>4)*8 + j
  unsigned short* bhi = (unsigned short*)(ws + WS_BHI);
  unsigned short* blo = (unsigned short*)(ws + WS_BLO);
  for (int i = t; i < 18432; i += stride) {
    int j  = i & 7;
    int l  = (i >> 3) & 63;
    int w  = (i >> 9) & 3;
    int tp = i >> 11;              // 0..8 = ky*3+kx
    int ch = w * 16 + (l & 15);
    int kc = ((l >> 4) << 3) + j;
    int ky = tp / 3, kx = tp - ky * 3;
    float v = w2[ch * 288 + kc * 9 + ky * 3 + kx];
    unsigned short h = f2bf_rne(v);
    bhi[i] = h;
    blo[i] = f2bf_rne(v - bf2f(h));
  }
  for (int i = t; i < 8192; i += stride) {       // wlt[i64][o128]
    int o = i & 127, ii = i >> 7;
    ws[WS_WLT + i] = wl[o * 64 + ii];
  }
}

// One block per patch, 256 threads = 4 waves.
// conv1 (vector f32): wave = (rowparity, colquad); lane = kc(32) x colhalf(2);
//   each lane: 8 output cols x 1 kc per produced row; relu -> bf16 hi/lo planes.
// conv2 (MFMA): wave w = channel tile (16 ch); per y2: 9 taps x 3 split-MFMAs,
//   A-frag = 1 ds_read_b128 per plane (lane m=x=lane&15, q=lane>>4 -> kc 8q..8q+7).
__global__ __launch_bounds__(256, 3) void patch_cnn_kernel(
    const float* __restrict__ imgG, const float* __restrict__ imgS,
    const float* __restrict__ kpG,  const float* __restrict__ kpS,
    const float* __restrict__ b1g,  const float* __restrict__ b2g,
    const float* __restrict__ blg,  float* __restrict__ ws) {
  __shared__ __align__(16) float patch[3 * Pp * PPAD];     // 14256 B
  __shared__ __align__(16) unsigned short hiP[PLSZ];       // 15360 B
  __shared__ __align__(16) unsigned short loP[PLSZ];       // 15360 B
  __shared__ __align__(16) float w1l[32 * 28];             // 3584 B
  __shared__ float b1l[32];
  __shared__ float gapv[64];
  // total ~= 48.9 KB -> 3 blocks/CU by LDS

  const int bid  = blockIdx.x;
  const int side = bid >> 10;
  const int rem  = bid & 1023;
  const int n    = rem >> 2;
  const int b    = rem & 3;
  const float* img = side ? imgS : imgG;
  const float* kp  = side ? kpS : kpG;
  const int tid  = threadIdx.x;
  const int wave = tid >> 6;
  const int lane = tid & 63;

  // conv1 roles
  const int rw  = wave & 1;                 // row within produced pair
  const int q8  = wave >> 1;                // col 16-group
  const int kcL = lane & 31;                // conv1 channel
  const int chf = lane >> 5;                // col 8-half
  const int c0  = q8 * 16 + chf * 8;        // first of 8 output cols
  // conv2 roles
  const int m = lane & 15;                  // x (A row); also D col = ch-in-tile
  const int q = lane >> 4;                  // kc quad

  int sx = (int)floorf(kp[n * 2 + 0] * 256.0f) - SIG;
  int sy = (int)floorf(kp[n * 2 + 1] * 256.0f) - SIG;
  sx = min(max(sx, 0), HW - Pp);
  sy = min(max(sy, 0), HW - Pp);

  // stage patch (zero pad cols)
  for (int i = tid; i < 3 * Pp * PPAD; i += 256) {
    int ci = i / (Pp * PPAD);
    int r2 = i - ci * (Pp * PPAD);
    int r  = r2 / PPAD;
    int cc = r2 - r * PPAD;
    float v = 0.0f;
    if (cc < Pp) v = img[((b * 3 + ci) * HW + (sy + r)) * HW + (sx + cc)];
    patch[i] = v;
  }
  for (int i = tid; i < 896; i += 256) w1l[i] = ws[WS_W1R + i];
  if (tid < 32) b1l[tid] = b1g[tid];

  // B-fragments (hi/lo) into registers: 9 taps x 16B each
  v8s bhF[9], blF[9];
  {
    const v8s* bh = (const v8s*)((const unsigned short*)(ws + WS_BHI));
    const v8s* bl = (const v8s*)((const unsigned short*)(ws + WS_BLO));
#pragma unroll
    for (int t = 0; t < 9; ++t) {
      bhF[t] = bh[(t * 4 + wave) * 64 + lane];
      blF[t] = bl[(t * 4 + wave) * 64 + lane];
    }
  }
  const float b2v = b2g[wave * 16 + m];
  float gapAcc = 0.0f;

  // ---- conv1 producer: rows r0,r0+1 -> plane slots ps,ps+1 ----
  auto produce = [&](int r0, int ps) {
    const int row = r0 + rw;
    if (row <= 30) {
      int sl = ps + rw; if (sl >= 6) sl -= 6;
      const float bb = b1l[kcL];
      float4 wv[7];
      const float4* wsrc = (const float4*)&w1l[kcL * 28];
#pragma unroll
      for (int u = 0; u < 7; ++u) wv[u] = wsrc[u];
      const float* wr = (const float*)wv;
      float o[8];
#pragma unroll
      for (int u = 0; u < 8; ++u) o[u] = bb;
#pragma unroll
      for (int ci = 0; ci < 3; ++ci) {
#pragma unroll
        for (int ky = 0; ky < 3; ++ky) {
          const float* pr = &patch[(ci * Pp + row + ky) * PPAD + c0];
          float4 A = *(const float4*)pr;
          float4 Bv = *(const float4*)(pr + 4);
          float2 Cv = *(const float2*)(pr + 8);
          float vv[10] = {A.x, A.y, A.z, A.w, Bv.x, Bv.y, Bv.z, Bv.w, Cv.x, Cv.y};
          const int k = (ci * 3 + ky) * 3;
#pragma unroll
          for (int kx = 0; kx < 3; ++kx)
#pragma unroll
            for (int u = 0; u < 8; ++u) o[u] = fmaf(vv[u + kx], wr[k + kx], o[u]);
        }
      }
#pragma unroll
      for (int u = 0; u < 8; ++u) {
        float f = fmaxf(o[u], 0.0f);
        unsigned short h = f2bf_rne(f);
        unsigned short lo = f2bf_rne(f - bf2f(h));
        const int c = c0 + u;
        const int idx = ((sl * 2 + (c & 1)) * 16 + (c >> 1)) * KCP + kcL;
        hiP[idx] = h;
        loP[idx] = lo;
      }
    }
  };

  __syncthreads();           // patch/w1l ready
  produce(0, 0);             // rows 0,1 -> slots 0,1
  produce(2, 2);             // rows 2,3 -> slots 2,3

  int s0 = 0;                // slot of row 2*y2
#pragma unroll 1
  for (int y2 = 0; y2 < 15; ++y2) {
    __syncthreads();         // prev-iter writes visible
    f32x4 acc = {0.f, 0.f, 0.f, 0.f};
#pragma unroll
    for (int ky = 0; ky < 3; ++ky) {
      int sk = s0 + ky; if (sk >= 6) sk -= 6;
#pragma unroll
      for (int kx = 0; kx < 3; ++kx) {
        const int p = kx & 1;
        int cp = m + (kx >> 1); if (cp > 15) cp = 15;   // x=15 is pad row anyway
        const int idx = ((sk * 2 + p) * 16 + cp) * KCP + q * 8;
        v8s ah = *(const v8s*)&hiP[idx];
        v8s al = *(const v8s*)&loP[idx];
        const int t = ky * 3 + kx;
        acc = __builtin_amdgcn_mfma_f32_16x16x32_bf16(ah, bhF[t], acc, 0, 0, 0);
        acc = __builtin_amdgcn_mfma_f32_16x16x32_bf16(ah, blF[t], acc, 0, 0, 0);
        acc = __builtin_amdgcn_mfma_f32_16x16x32_bf16(al, bhF[t], acc, 0, 0, 0);
      }
    }
    // D[row=x=4q+r][col=ch=m]: bias+relu+sum over x (mask x==15)
    {
      float s = fmaxf(acc.x + b2v, 0.f) + fmaxf(acc.y + b2v, 0.f) +
                fmaxf(acc.z + b2v, 0.f);
      if (q < 3) s += fmaxf(acc.w + b2v, 0.f);
      gapAcc += s;
    }
    // produce rows 2*y2+4, 2*y2+5 into slots (s0+4)%6, (s0+5)%6
    const int r0 = 2 * y2 + 4;
    if (r0 <= 30) {
      int ps = s0 + 4; if (ps >= 6) ps -= 6;
      produce(r0, ps);
    }
    s0 += 2; if (s0 >= 6) s0 -= 6;
  }

  // reduce gapAcc over kc-quads (lanes m, m+16, m+32, m+48)
  gapAcc += __shfl_down(gapAcc, 32, 64);
  gapAcc += __shfl_down(gapAcc, 16, 64);
  if (lane < 16) gapv[wave * 16 + m] = gapAcc * (1.0f / 225.0f);
  __syncthreads();

  if (tid < OUTF) {
    float f = blg[tid];
#pragma unroll 8
    for (int i = 0; i < 64; ++i) f = fmaf(gapv[i], ws[WS_WLT + i * OUTF + tid], f);
    ws[WS_FEAT + ((side * Nn + n) * Bb + b) * OUTF + tid] = f;
  }
}

__global__ __launch_bounds__(256) void loss_part(const float* __restrict__ wsf,
                                                 double* __restrict__ parts) {
  const float* fg = wsf + WS_FEAT;
  const float* fs = fg + FEAT_PER_SIDE;
  double s = 0.0;
  for (int i = blockIdx.x * 256 + threadIdx.x; i < FEAT_PER_SIDE; i += 64 * 256) {
    double d = (double)fg[i] - (double)fs[i];
    s += d * d;
  }
  __shared__ double red[256];
  red[threadIdx.x] = s;
  __syncthreads();
  for (int off = 128; off > 0; off >>= 1) {
    if (threadIdx.x < off) red[threadIdx.x] += red[threadIdx.x + off];
    __syncthreads();
  }
  if (threadIdx.x == 0) parts[blockIdx.x] = red[0];
}

__global__ void loss_final(float* __restrict__ out, const double* __restrict__ parts) {
  double s = parts[threadIdx.x];
#pragma unroll
  for (int off = 32; off > 0; off >>= 1) s += __shfl_down(s, off, 64);
  if (threadIdx.x == 0) out[0] = (float)(s / (double)FEAT_PER_SIDE);
}

extern "C" void kernel_launch(void* const* d_in, const int* in_sizes, int n_in,
                              void* d_out, int out_size, void* d_ws, size_t ws_size,
                              hipStream_t stream) {
  const float* imgG = (const float*)d_in[0];
  const float* imgS = (const float*)d_in[1];
  const float* kpG  = (const float*)d_in[2];
  const float* kpS  = (const float*)d_in[3];
  const float* w1   = (const float*)d_in[4];
  const float* b1   = (const float*)d_in[5];
  const float* w2   = (const float*)d_in[6];
  const float* b2   = (const float*)d_in[7];
  const float* wl   = (const float*)d_in[8];
  const float* bl   = (const float*)d_in[9];
  float* ws  = (float*)d_ws;
  float* out = (float*)d_out;
  double* parts = (double*)((char*)d_ws + (size_t)WS_PART * 4);

  hipLaunchKernelGGL(prep_kernel, dim3(32), dim3(256), 0, stream, w1, w2, wl, ws);
  hipLaunchKernelGGL(patch_cnn_kernel, dim3(2048), dim3(256), 0, stream,
                     imgG, imgS, kpG, kpS, b1, b2, bl, ws);
  hipLaunchKernelGGL(loss_part, dim3(64), dim3(256), 0, stream, ws, parts);
  hipLaunchKernelGGL(loss_final, dim3(1), dim3(64), 0, stream, out, parts);
}